// Round 1
// baseline (384.540 us; speedup 1.0000x reference)
//
#include <hip/hip_runtime.h>
#include <math.h>

#define N_ROWS 32768
#define DIM    1024
#define NE     64
#define KTOP   8
#define MB     64     // rows per block
#define BK     128    // K-chunk staged in LDS
#define NCHUNK (DIM / BK)

// XOR swizzle: keeps 16B alignment (xor with multiple of 4), spreads the
// 16-distinct-address W-operand b128 reads across all 32 banks (2-way max),
// X-operand reads (4 distinct addrs/wave) conflict-free.
__device__ __forceinline__ int sw_idx(int i, int k) {
    return i * BK + (k ^ (((i >> 2) & 7) << 2));
}

extern "C" __global__ void __launch_bounds__(256, 2)
moe_gate_kernel(const float* __restrict__ x, const float* __restrict__ gwm,
                const float* __restrict__ nw, const float* __restrict__ noise,
                float* __restrict__ out0, float* __restrict__ out1,
                double* __restrict__ esum) {
    __shared__ float xs[MB * BK];    // 32 KB; reused as logits[64][65] in epilogue
    __shared__ float wsm[NE * BK];   // 32 KB; reused as per-wave expert partials

    const int tid  = threadIdx.x;
    const int row0 = blockIdx.x * MB;
    const int tx   = tid & 15;   // expert group (4 experts each)
    const int ty   = tid >> 4;   // row group   (4 rows each)

    float acc[4][4];
#pragma unroll
    for (int r = 0; r < 4; ++r)
#pragma unroll
        for (int c = 0; c < 4; ++c) acc[r][c] = 0.f;

    // ---- GEMM: logits[64 rows][64 experts] = x_tile @ gate_w^T ----
    float4 xreg[8], wreg[8];
#pragma unroll
    for (int i = 0; i < 8; ++i) {          // preload chunk 0
        int f = tid + i * 256; int rr = f >> 5; int k0 = (f & 31) << 2;
        xreg[i] = *(const float4*)&x  [(size_t)(row0 + rr) * DIM + k0];
        wreg[i] = *(const float4*)&gwm[(size_t)rr * DIM + k0];
    }

    for (int ch = 0; ch < NCHUNK; ++ch) {
        __syncthreads();
#pragma unroll
        for (int i = 0; i < 8; ++i) {
            int f = tid + i * 256; int rr = f >> 5; int k0 = (f & 31) << 2;
            *(float4*)&xs [sw_idx(rr, k0)] = xreg[i];
            *(float4*)&wsm[sw_idx(rr, k0)] = wreg[i];
        }
        __syncthreads();
        if (ch < NCHUNK - 1) {             // prefetch next chunk (overlaps compute)
            int kk = (ch + 1) * BK;
#pragma unroll
            for (int i = 0; i < 8; ++i) {
                int f = tid + i * 256; int rr = f >> 5; int k0 = (f & 31) << 2;
                xreg[i] = *(const float4*)&x  [(size_t)(row0 + rr) * DIM + kk + k0];
                wreg[i] = *(const float4*)&gwm[(size_t)rr * DIM + kk + k0];
            }
        }
#pragma unroll 4
        for (int k0 = 0; k0 < BK; k0 += 4) {
            float4 xa[4], wb[4];
#pragma unroll
            for (int r = 0; r < 4; ++r) xa[r] = *(const float4*)&xs [sw_idx(4 * ty + r, k0)];
#pragma unroll
            for (int c = 0; c < 4; ++c) wb[c] = *(const float4*)&wsm[sw_idx(4 * tx + c, k0)];
#pragma unroll
            for (int r = 0; r < 4; ++r)
#pragma unroll
                for (int c = 0; c < 4; ++c) {
                    acc[r][c] = fmaf(xa[r].x, wb[c].x, acc[r][c]);
                    acc[r][c] = fmaf(xa[r].y, wb[c].y, acc[r][c]);
                    acc[r][c] = fmaf(xa[r].z, wb[c].z, acc[r][c]);
                    acc[r][c] = fmaf(xa[r].w, wb[c].w, acc[r][c]);
                }
        }
    }

    // ---- epilogue: store logits to LDS (stride 65 -> 2-way max on reads) ----
    __syncthreads();                       // all compute reads of xs/wsm done
#pragma unroll
    for (int r = 0; r < 4; ++r)
#pragma unroll
        for (int c = 0; c < 4; ++c)
            xs[(4 * ty + r) * 65 + 4 * tx + c] = acc[r][c];
    __syncthreads();

    const int w    = tid >> 6;             // wave id 0..3, handles 16 rows
    const int lane = tid & 63;             // lane = expert
    const float nwl = nw[lane];
    float epart = 0.f;                     // running sum of gate_weights for this expert

    for (int i = 0; i < 16; ++i) {
        const int   lrow = w * 16 + i;
        const size_t grow = (size_t)(row0 + lrow);
        const float lg = xs[lrow * 65 + lane];

        // dense softmax over 64 experts (for load-balance mean)
        float m = lg;
#pragma unroll
        for (int off = 32; off; off >>= 1) m = fmaxf(m, __shfl_xor(m, off));
        float p = __expf(lg - m);
        float s = p;
#pragma unroll
        for (int off = 32; off; off >>= 1) s += __shfl_xor(s, off);
        epart += p / s;

        // noisy logits + iterative top-8 (tie -> lower index, jax semantics)
        const float nz    = noise[grow * NE + lane];
        const float noisy = fmaf(nz, nwl, lg);
        float cur  = noisy;
        bool  sel  = false;
        float mtop = 0.f;
        int   myid = 0;
#pragma unroll
        for (int j = 0; j < KTOP; ++j) {
            float v = cur; int id = lane;
#pragma unroll
            for (int off = 32; off; off >>= 1) {
                float ov = __shfl_xor(v, off);
                int   oi = __shfl_xor(id, off);
                if (ov > v || (ov == v && oi < id)) { v = ov; id = oi; }
            }
            if (j == 0) mtop = v;
            if (lane == id) { sel = true; cur = -INFINITY; }
            if (lane == j) myid = id;
        }

        float swv = sel ? __expf(noisy - mtop) : 0.f;
        float ssum = swv;
#pragma unroll
        for (int off = 32; off; off >>= 1) ssum += __shfl_xor(ssum, off);

        out0[grow * NE + lane] = swv / ssum;               // coalesced 256B/row
        if (lane < KTOP) out1[grow * KTOP + lane] = (float)myid;
    }

    // combine per-wave expert partials -> one double atomic per expert per block
    wsm[w * 64 + lane] = epart;
    __syncthreads();
    if (tid < 64) {
        float t = wsm[tid] + wsm[64 + tid] + wsm[128 + tid] + wsm[192 + tid];
        atomicAdd(&esum[tid], (double)t);
    }
}

extern "C" __global__ void moe_loss_kernel(const double* __restrict__ esum,
                                           float* __restrict__ lossp) {
    int e = threadIdx.x;                   // 64 threads = 1 wave
    double mean = esum[e] * (1.0 / 32768.0);
    double d = mean - (1.0 / 64.0);
    double sq = d * d;
#pragma unroll
    for (int off = 32; off; off >>= 1) sq += __shfl_xor(sq, off);
    if (e == 0) lossp[0] = (float)(sq * (1.0 / 64.0) * 0.01);
}

extern "C" void kernel_launch(void* const* d_in, const int* in_sizes, int n_in,
                              void* d_out, int out_size, void* d_ws, size_t ws_size,
                              hipStream_t stream) {
    const float* x     = (const float*)d_in[0];   // [32768,1024]
    const float* gw    = (const float*)d_in[1];   // [64,1024]
    const float* nw    = (const float*)d_in[2];   // [64]
    const float* noise = (const float*)d_in[3];   // [32768,64]

    float* out0  = (float*)d_out;                       // [32768,64] gated weights
    float* out1  = out0 + (size_t)N_ROWS * NE;          // [32768,8] ids as f32
    float* lossp = out1 + (size_t)N_ROWS * KTOP;        // scalar
    double* esum = (double*)d_ws;                       // [64] expert gw sums

    hipMemsetAsync(d_ws, 0, NE * sizeof(double), stream);
    moe_gate_kernel<<<N_ROWS / MB, 256, 0, stream>>>(x, gw, nw, noise, out0, out1, esum);
    moe_loss_kernel<<<1, 64, 0, stream>>>(esum, lossp);
}